// Round 6
// baseline (2584.319 us; speedup 1.0000x reference)
//
#include <hip/hip_runtime.h>
#include <math.h>

// T=1000, B=256, F_IN=13 x3 -> 39 features, H=100, 3H=300 (gate order r,z,n), 20 classes
#define T_STEPS 1000
#define BATCH   256
#define FIN     13
#define XDIM    39
#define XPAD    40
#define HDIM    100
#define G3      300
#define NCLS    20
#define NTHR    640    // 2 threads per gate row: part0 = tid<320 (rows 0..299), part1 = tid-320
#define SPLIT   28     // part0 covers h[0:28]; part1 covers h[28:100] (72 elems)

__device__ __forceinline__ float fast_sigmoid(float v) {
    return 1.f / (1.f + __expf(-v));
}
__device__ __forceinline__ float fast_tanh(float v) {
    const float c = fminf(fmaxf(v, -15.f), 15.f);
    const float e = __expf(2.f * c);
    return (e - 1.f) / (e + 1.f);
}

// 4 independent accumulator chains (FMA latency ~4 cyc). Inline fn, not macro
// (macro param `w` would collide with the .w member token — R3 lesson).
__device__ __forceinline__ void fma4(const float4& wv, const float4& xv,
                                     float& a0, float& a1, float& a2, float& a3)
{
    a0 = fmaf(wv.x, xv.x, a0);
    a1 = fmaf(wv.y, xv.y, a1);
    a2 = fmaf(wv.z, xv.z, a2);
    a3 = fmaf(wv.w, xv.w, a3);
}

// R4/R5 lesson: the allocator refuses ~140 resident floats/thread (keeps ~88 and
// remats weight loads -> L2-BW bound at ~39 TB/s = the ceiling). Halve the
// per-thread weight footprint to ~70 floats by splitting each row across two
// threads; ~110 total pressure sits under the heuristic. launch_bounds(640,3):
// VGPR budget 512/3 = 170 >= need, and 10 waves stay co-residable.
__launch_bounds__(NTHR, 3)
__global__ void gru_persistent(const float* __restrict__ mfcc0,
                               const float* __restrict__ mfcc1,
                               const float* __restrict__ mfcc2,
                               const float* __restrict__ len0,
                               const float* __restrict__ W_ih,
                               const float* __restrict__ W_hh,
                               const float* __restrict__ b_ih,
                               const float* __restrict__ b_hh,
                               const float* __restrict__ W_out,
                               const float* __restrict__ b_out,
                               float* __restrict__ out)
{
    const int b   = blockIdx.x;
    const int tid = threadIdx.x;
    const bool pa = (tid < 320);                    // part0: waves 0-4, part1: waves 5-9
    const int g0  = pa ? tid : (tid - 320);         // unclamped row id
    const int g   = (g0 < G3) ? g0 : (G3 - 1);      // clamped; stores guarded by g0

    __shared__ __align__(16) float h_lds[2][HDIM];
    __shared__ __align__(16) float x_lds[2][XPAD];
    __shared__ float p0a[G3];        // part0: ai + bi            (input-gate part)
    __shared__ float p0h[G3];        // part0: ah(h[0:28]) + bh   (hidden part, low)
    __shared__ float p1h[G3];        // part1: ah(h[28:100])      (hidden part, high)
    __shared__ float feat[2 * HDIM];

    // ---- one-time: this thread's weight slice into 18 named float4s ----
    float4 q0, q1, q2, q3, q4, q5, q6, q7, q8, q9, q10, q11, q12, q13, q14, q15, q16, q17;
    if (pa) {
        const float* wi = W_ih + g * XDIM;          // 39 floats, scalar gather
#define LDA(i) make_float4(wi[4*(i)], wi[4*(i)+1], wi[4*(i)+2], wi[4*(i)+3])
        q0 = LDA(0); q1 = LDA(1); q2 = LDA(2); q3 = LDA(3); q4 = LDA(4);
        q5 = LDA(5); q6 = LDA(6); q7 = LDA(7); q8 = LDA(8);
        q9 = make_float4(wi[36], wi[37], wi[38], 0.f);   // pad pairs with x_lds[39]==0
#undef LDA
        const float4* wh = (const float4*)(W_hh + g * HDIM);      // 400B row: 16B aligned
        q10 = wh[0]; q11 = wh[1]; q12 = wh[2]; q13 = wh[3];
        q14 = wh[4]; q15 = wh[5]; q16 = wh[6];                    // h[0:28]
        q17 = make_float4(0.f, 0.f, 0.f, 0.f);
    } else {
        const float4* wh = (const float4*)(W_hh + g * HDIM + SPLIT); // +112B: 16B aligned
        q0  = wh[0];  q1  = wh[1];  q2  = wh[2];  q3  = wh[3];  q4  = wh[4];
        q5  = wh[5];  q6  = wh[6];  q7  = wh[7];  q8  = wh[8];  q9  = wh[9];
        q10 = wh[10]; q11 = wh[11]; q12 = wh[12]; q13 = wh[13]; q14 = wh[14];
        q15 = wh[15]; q16 = wh[16]; q17 = wh[17];                 // h[28:100]
    }
    const float bi = pa ? b_ih[g] : 0.f;
    const float bh = pa ? b_hh[g] : 0.f;

    // ---- per-thread x streaming source (threads 0..38, inside part0) ----
    const float* xsrc = mfcc0;
    int xoff = 0;
    if (tid < XDIM) {
        const int f = tid % FIN;
        xsrc = (tid < FIN) ? mfcc0 : (tid < 2 * FIN ? mfcc1 : mfcc2);
        xoff = b * FIN + f;
    }

    if (tid < HDIM) h_lds[0][tid] = 0.f;
    if (tid < XDIM) x_lds[0][tid] = xsrc[xoff];
    if (tid == XDIM) { x_lds[0][XDIM] = 0.f; x_lds[1][XDIM] = 0.f; }
    __syncthreads();

    float sum = 0.f;
    float mx  = -INFINITY;

    for (int t = 0; t < T_STEPS; ++t) {
        const int cur = t & 1;
        const int nxt = cur ^ 1;

        float xpf = 0.f;     // prefetch x(t+1) during compute
        if (tid < XDIM && (t + 1) < T_STEPS)
            xpf = xsrc[(size_t)(t + 1) * (BATCH * FIN) + xoff];

        // ---- phase A: partial dot products (divergence is wave-granular) ----
        if (pa) {
            const float4* x4 = (const float4*)x_lds[cur];
            float i0 = 0.f, i1 = 0.f, i2 = 0.f, i3 = 0.f;
            float4 vv;
            vv = x4[0]; fma4(q0, vv, i0, i1, i2, i3);
            vv = x4[1]; fma4(q1, vv, i0, i1, i2, i3);
            vv = x4[2]; fma4(q2, vv, i0, i1, i2, i3);
            vv = x4[3]; fma4(q3, vv, i0, i1, i2, i3);
            vv = x4[4]; fma4(q4, vv, i0, i1, i2, i3);
            vv = x4[5]; fma4(q5, vv, i0, i1, i2, i3);
            vv = x4[6]; fma4(q6, vv, i0, i1, i2, i3);
            vv = x4[7]; fma4(q7, vv, i0, i1, i2, i3);
            vv = x4[8]; fma4(q8, vv, i0, i1, i2, i3);
            vv = x4[9]; fma4(q9, vv, i0, i1, i2, i3);

            const float4* h4 = (const float4*)h_lds[cur];        // h[0:28]
            float g0a = 0.f, g1a = 0.f, g2a = 0.f, g3a = 0.f;
            vv = h4[0]; fma4(q10, vv, g0a, g1a, g2a, g3a);
            vv = h4[1]; fma4(q11, vv, g0a, g1a, g2a, g3a);
            vv = h4[2]; fma4(q12, vv, g0a, g1a, g2a, g3a);
            vv = h4[3]; fma4(q13, vv, g0a, g1a, g2a, g3a);
            vv = h4[4]; fma4(q14, vv, g0a, g1a, g2a, g3a);
            vv = h4[5]; fma4(q15, vv, g0a, g1a, g2a, g3a);
            vv = h4[6]; fma4(q16, vv, g0a, g1a, g2a, g3a);
            if (g0 < G3) {
                p0a[g0] = bi + ((i0 + i1) + (i2 + i3));
                p0h[g0] = bh + ((g0a + g1a) + (g2a + g3a));
            }
        } else {
            const float4* h4 = (const float4*)(&h_lds[cur][SPLIT]);   // h[28:100]
            float g0a = 0.f, g1a = 0.f, g2a = 0.f, g3a = 0.f;
            float4 vv;
            vv = h4[0];  fma4(q0,  vv, g0a, g1a, g2a, g3a);
            vv = h4[1];  fma4(q1,  vv, g0a, g1a, g2a, g3a);
            vv = h4[2];  fma4(q2,  vv, g0a, g1a, g2a, g3a);
            vv = h4[3];  fma4(q3,  vv, g0a, g1a, g2a, g3a);
            vv = h4[4];  fma4(q4,  vv, g0a, g1a, g2a, g3a);
            vv = h4[5];  fma4(q5,  vv, g0a, g1a, g2a, g3a);
            vv = h4[6];  fma4(q6,  vv, g0a, g1a, g2a, g3a);
            vv = h4[7];  fma4(q7,  vv, g0a, g1a, g2a, g3a);
            vv = h4[8];  fma4(q8,  vv, g0a, g1a, g2a, g3a);
            vv = h4[9];  fma4(q9,  vv, g0a, g1a, g2a, g3a);
            vv = h4[10]; fma4(q10, vv, g0a, g1a, g2a, g3a);
            vv = h4[11]; fma4(q11, vv, g0a, g1a, g2a, g3a);
            vv = h4[12]; fma4(q12, vv, g0a, g1a, g2a, g3a);
            vv = h4[13]; fma4(q13, vv, g0a, g1a, g2a, g3a);
            vv = h4[14]; fma4(q14, vv, g0a, g1a, g2a, g3a);
            vv = h4[15]; fma4(q15, vv, g0a, g1a, g2a, g3a);
            vv = h4[16]; fma4(q16, vv, g0a, g1a, g2a, g3a);
            vv = h4[17]; fma4(q17, vv, g0a, g1a, g2a, g3a);
            if (g0 < G3)
                p1h[g0] = (g0a + g1a) + (g2a + g3a);
        }
        if (tid < XDIM) x_lds[nxt][tid] = xpf;
        __syncthreads();

        // ---- phase B: nonlinearity + state update (threads 0..99) ----
        if (tid < HDIM) {
            const float r  = fast_sigmoid(p0a[tid] + p0h[tid] + p1h[tid]);
            const float z  = fast_sigmoid(p0a[HDIM + tid] + p0h[HDIM + tid] + p1h[HDIM + tid]);
            const float hn = p0h[2*HDIM + tid] + p1h[2*HDIM + tid];
            const float n  = fast_tanh(fmaf(r, hn, p0a[2*HDIM + tid]));
            const float ho = h_lds[cur][tid];
            const float hv = fmaf(z, ho - n, n);    // (1-z)*n + z*h
            h_lds[nxt][tid] = hv;
            sum += hv;
            mx = fmaxf(mx, hv);
        }
        __syncthreads();
    }

    // ---- pooling + output linear ----
    if (tid < HDIM) {
        feat[tid]        = sum / len0[b];
        feat[HDIM + tid] = mx;
    }
    __syncthreads();

    if (tid < NCLS) {
        float acc = b_out[tid];
        #pragma unroll 4
        for (int k = 0; k < 2 * HDIM; ++k)
            acc = fmaf(W_out[tid * 2 * HDIM + k], feat[k], acc);
        out[b * NCLS + tid] = acc;
    }
}

extern "C" void kernel_launch(void* const* d_in, const int* in_sizes, int n_in,
                              void* d_out, int out_size, void* d_ws, size_t ws_size,
                              hipStream_t stream)
{
    const float* mfcc0 = (const float*)d_in[0];
    const float* mfcc1 = (const float*)d_in[1];
    const float* mfcc2 = (const float*)d_in[2];
    const float* len0  = (const float*)d_in[3];
    const float* W_ih  = (const float*)d_in[4];
    const float* W_hh  = (const float*)d_in[5];
    const float* b_ih  = (const float*)d_in[6];
    const float* b_hh  = (const float*)d_in[7];
    const float* W_out = (const float*)d_in[8];
    const float* b_out = (const float*)d_in[9];
    float* out = (float*)d_out;

    gru_persistent<<<BATCH, NTHR, 0, stream>>>(
        mfcc0, mfcc1, mfcc2, len0, W_ih, W_hh, b_ih, b_hh, W_out, b_out, out);
}

// Round 7
// 1663.589 us; speedup vs baseline: 1.5535x; 1.5535x over previous
//
#include <hip/hip_runtime.h>
#include <math.h>

// T=1000, B=256, F_IN=13 x3 -> 39 features, H=100, 3H=300 (gate order r,z,n), 20 classes
#define T_STEPS 1000
#define BATCH   256
#define FIN     13
#define XDIM    39
#define XPAD    40
#define HDIM    100
#define G3      300
#define NCLS    20

__device__ __forceinline__ float fast_sigmoid(float v) {
    return 1.f / (1.f + __expf(-v));
}
__device__ __forceinline__ float fast_tanh(float v) {
    const float c = fminf(fmaxf(v, -15.f), 15.f);
    const float e = __expf(2.f * c);
    return (e - 1.f) / (e + 1.f);
}

// R4: plain loads get rematerialized every step (L2-BW bound at ~39 TB/s).
// R5: "+v" pins on float4 MEMBERS force the aggregate to an alloca -> scratch.
// R6: launch_bounds(640,3) capped VGPR at ~102 -> wholesale spill (WRITE_SIZE 29MB).
// R7: pin 139 plain SCALAR floats (not aggregate members) under a 256-VGPR
// budget (launch_bounds(320,1)). A pinned scalar can't be remat'd (opaque
// origin) and can't alloca (not a member) -> must stay in a VGPR.
#define PIN8(a0,a1,a2,a3,a4,a5,a6,a7) \
    asm volatile("" : "+v"(a0),"+v"(a1),"+v"(a2),"+v"(a3),"+v"(a4),"+v"(a5),"+v"(a6),"+v"(a7))
#define PIN4(a0,a1,a2,a3) \
    asm volatile("" : "+v"(a0),"+v"(a1),"+v"(a2),"+v"(a3))
#define PIN3(a0,a1,a2) \
    asm volatile("" : "+v"(a0),"+v"(a1),"+v"(a2))

__launch_bounds__(320, 1)
__global__ void gru_persistent(const float* __restrict__ mfcc0,
                               const float* __restrict__ mfcc1,
                               const float* __restrict__ mfcc2,
                               const float* __restrict__ len0,
                               const float* __restrict__ W_ih,
                               const float* __restrict__ W_hh,
                               const float* __restrict__ b_ih,
                               const float* __restrict__ b_hh,
                               const float* __restrict__ W_out,
                               const float* __restrict__ b_out,
                               float* __restrict__ out)
{
    const int b   = blockIdx.x;
    const int tid = threadIdx.x;
    const int row = (tid < G3) ? tid : (G3 - 1);   // clamp; stores are guarded

    __shared__ __align__(16) float h_lds[2][HDIM];
    __shared__ __align__(16) float x_lds[2][XPAD];
    __shared__ float gates[G3];      // r,z rows: gi+gh ; n rows: gi
    __shared__ float ghn[HDIM];      // n rows: gh part (scaled by r)
    __shared__ float feat[2 * HDIM];

    // ---- one-time: weight row into 139 named scalar registers ----
    const float* wi = W_ih + row * XDIM;
    const float* wh = W_hh + row * HDIM;

    float w00=wi[ 0], w01=wi[ 1], w02=wi[ 2], w03=wi[ 3], w04=wi[ 4], w05=wi[ 5], w06=wi[ 6], w07=wi[ 7];
    float w08=wi[ 8], w09=wi[ 9], w10=wi[10], w11=wi[11], w12=wi[12], w13=wi[13], w14=wi[14], w15=wi[15];
    float w16=wi[16], w17=wi[17], w18=wi[18], w19=wi[19], w20=wi[20], w21=wi[21], w22=wi[22], w23=wi[23];
    float w24=wi[24], w25=wi[25], w26=wi[26], w27=wi[27], w28=wi[28], w29=wi[29], w30=wi[30], w31=wi[31];
    float w32=wi[32], w33=wi[33], w34=wi[34], w35=wi[35], w36=wi[36], w37=wi[37], w38=wi[38];

    float u00=wh[ 0], u01=wh[ 1], u02=wh[ 2], u03=wh[ 3], u04=wh[ 4], u05=wh[ 5], u06=wh[ 6], u07=wh[ 7];
    float u08=wh[ 8], u09=wh[ 9], u10=wh[10], u11=wh[11], u12=wh[12], u13=wh[13], u14=wh[14], u15=wh[15];
    float u16=wh[16], u17=wh[17], u18=wh[18], u19=wh[19], u20=wh[20], u21=wh[21], u22=wh[22], u23=wh[23];
    float u24=wh[24], u25=wh[25], u26=wh[26], u27=wh[27], u28=wh[28], u29=wh[29], u30=wh[30], u31=wh[31];
    float u32=wh[32], u33=wh[33], u34=wh[34], u35=wh[35], u36=wh[36], u37=wh[37], u38=wh[38], u39=wh[39];
    float u40=wh[40], u41=wh[41], u42=wh[42], u43=wh[43], u44=wh[44], u45=wh[45], u46=wh[46], u47=wh[47];
    float u48=wh[48], u49=wh[49], u50=wh[50], u51=wh[51], u52=wh[52], u53=wh[53], u54=wh[54], u55=wh[55];
    float u56=wh[56], u57=wh[57], u58=wh[58], u59=wh[59], u60=wh[60], u61=wh[61], u62=wh[62], u63=wh[63];
    float u64=wh[64], u65=wh[65], u66=wh[66], u67=wh[67], u68=wh[68], u69=wh[69], u70=wh[70], u71=wh[71];
    float u72=wh[72], u73=wh[73], u74=wh[74], u75=wh[75], u76=wh[76], u77=wh[77], u78=wh[78], u79=wh[79];
    float u80=wh[80], u81=wh[81], u82=wh[82], u83=wh[83], u84=wh[84], u85=wh[85], u86=wh[86], u87=wh[87];
    float u88=wh[88], u89=wh[89], u90=wh[90], u91=wh[91], u92=wh[92], u93=wh[93], u94=wh[94], u95=wh[95];
    float u96=wh[96], u97=wh[97], u98=wh[98], u99=wh[99];

    // Pin all 139 scalars into VGPRs (see comment at PIN8).
    PIN8(w00,w01,w02,w03,w04,w05,w06,w07);
    PIN8(w08,w09,w10,w11,w12,w13,w14,w15);
    PIN8(w16,w17,w18,w19,w20,w21,w22,w23);
    PIN8(w24,w25,w26,w27,w28,w29,w30,w31);
    PIN4(w32,w33,w34,w35); PIN3(w36,w37,w38);
    PIN8(u00,u01,u02,u03,u04,u05,u06,u07);
    PIN8(u08,u09,u10,u11,u12,u13,u14,u15);
    PIN8(u16,u17,u18,u19,u20,u21,u22,u23);
    PIN8(u24,u25,u26,u27,u28,u29,u30,u31);
    PIN8(u32,u33,u34,u35,u36,u37,u38,u39);
    PIN8(u40,u41,u42,u43,u44,u45,u46,u47);
    PIN8(u48,u49,u50,u51,u52,u53,u54,u55);
    PIN8(u56,u57,u58,u59,u60,u61,u62,u63);
    PIN8(u64,u65,u66,u67,u68,u69,u70,u71);
    PIN8(u72,u73,u74,u75,u76,u77,u78,u79);
    PIN8(u80,u81,u82,u83,u84,u85,u86,u87);
    PIN8(u88,u89,u90,u91,u92,u93,u94,u95);
    PIN4(u96,u97,u98,u99);

    const float bi = b_ih[row];
    const float bh = b_hh[row];

    // ---- per-thread x streaming source (threads 0..38) ----
    const float* xsrc = mfcc0;
    int xoff = 0;
    if (tid < XDIM) {
        const int f = tid % FIN;
        xsrc = (tid < FIN) ? mfcc0 : (tid < 2 * FIN ? mfcc1 : mfcc2);
        xoff = b * FIN + f;
    }

    if (tid < HDIM) h_lds[0][tid] = 0.f;
    if (tid < XDIM) x_lds[0][tid] = xsrc[xoff];
    if (tid == XDIM) { x_lds[0][XDIM] = 0.f; x_lds[1][XDIM] = 0.f; }
    __syncthreads();

    float sum = 0.f;
    float mx  = -INFINITY;

    for (int t = 0; t < T_STEPS; ++t) {
        const int cur = t & 1;
        const int nxt = cur ^ 1;

        float xpf = 0.f;     // prefetch x(t+1) during compute
        if (tid < XDIM && (t + 1) < T_STEPS)
            xpf = xsrc[(size_t)(t + 1) * (BATCH * FIN) + xoff];

        // ---- phase A: gate pre-activations (uniform control flow) ----
        const float4* x4 = (const float4*)x_lds[cur];
        const float4* h4 = (const float4*)h_lds[cur];

        float i0 = 0.f, i1 = 0.f, i2 = 0.f, i3 = 0.f;
        float4 vv;
        vv = x4[0]; i0=fmaf(w00,vv.x,i0); i1=fmaf(w01,vv.y,i1); i2=fmaf(w02,vv.z,i2); i3=fmaf(w03,vv.w,i3);
        vv = x4[1]; i0=fmaf(w04,vv.x,i0); i1=fmaf(w05,vv.y,i1); i2=fmaf(w06,vv.z,i2); i3=fmaf(w07,vv.w,i3);
        vv = x4[2]; i0=fmaf(w08,vv.x,i0); i1=fmaf(w09,vv.y,i1); i2=fmaf(w10,vv.z,i2); i3=fmaf(w11,vv.w,i3);
        vv = x4[3]; i0=fmaf(w12,vv.x,i0); i1=fmaf(w13,vv.y,i1); i2=fmaf(w14,vv.z,i2); i3=fmaf(w15,vv.w,i3);
        vv = x4[4]; i0=fmaf(w16,vv.x,i0); i1=fmaf(w17,vv.y,i1); i2=fmaf(w18,vv.z,i2); i3=fmaf(w19,vv.w,i3);
        vv = x4[5]; i0=fmaf(w20,vv.x,i0); i1=fmaf(w21,vv.y,i1); i2=fmaf(w22,vv.z,i2); i3=fmaf(w23,vv.w,i3);
        vv = x4[6]; i0=fmaf(w24,vv.x,i0); i1=fmaf(w25,vv.y,i1); i2=fmaf(w26,vv.z,i2); i3=fmaf(w27,vv.w,i3);
        vv = x4[7]; i0=fmaf(w28,vv.x,i0); i1=fmaf(w29,vv.y,i1); i2=fmaf(w30,vv.z,i2); i3=fmaf(w31,vv.w,i3);
        vv = x4[8]; i0=fmaf(w32,vv.x,i0); i1=fmaf(w33,vv.y,i1); i2=fmaf(w34,vv.z,i2); i3=fmaf(w35,vv.w,i3);
        vv = x4[9]; i0=fmaf(w36,vv.x,i0); i1=fmaf(w37,vv.y,i1); i2=fmaf(w38,vv.z,i2);
        const float ai = bi + ((i0 + i1) + (i2 + i3));

        float g0 = 0.f, g1 = 0.f, g2 = 0.f, g3 = 0.f;
        vv = h4[ 0]; g0=fmaf(u00,vv.x,g0); g1=fmaf(u01,vv.y,g1); g2=fmaf(u02,vv.z,g2); g3=fmaf(u03,vv.w,g3);
        vv = h4[ 1]; g0=fmaf(u04,vv.x,g0); g1=fmaf(u05,vv.y,g1); g2=fmaf(u06,vv.z,g2); g3=fmaf(u07,vv.w,g3);
        vv = h4[ 2]; g0=fmaf(u08,vv.x,g0); g1=fmaf(u09,vv.y,g1); g2=fmaf(u10,vv.z,g2); g3=fmaf(u11,vv.w,g3);
        vv = h4[ 3]; g0=fmaf(u12,vv.x,g0); g1=fmaf(u13,vv.y,g1); g2=fmaf(u14,vv.z,g2); g3=fmaf(u15,vv.w,g3);
        vv = h4[ 4]; g0=fmaf(u16,vv.x,g0); g1=fmaf(u17,vv.y,g1); g2=fmaf(u18,vv.z,g2); g3=fmaf(u19,vv.w,g3);
        vv = h4[ 5]; g0=fmaf(u20,vv.x,g0); g1=fmaf(u21,vv.y,g1); g2=fmaf(u22,vv.z,g2); g3=fmaf(u23,vv.w,g3);
        vv = h4[ 6]; g0=fmaf(u24,vv.x,g0); g1=fmaf(u25,vv.y,g1); g2=fmaf(u26,vv.z,g2); g3=fmaf(u27,vv.w,g3);
        vv = h4[ 7]; g0=fmaf(u28,vv.x,g0); g1=fmaf(u29,vv.y,g1); g2=fmaf(u30,vv.z,g2); g3=fmaf(u31,vv.w,g3);
        vv = h4[ 8]; g0=fmaf(u32,vv.x,g0); g1=fmaf(u33,vv.y,g1); g2=fmaf(u34,vv.z,g2); g3=fmaf(u35,vv.w,g3);
        vv = h4[ 9]; g0=fmaf(u36,vv.x,g0); g1=fmaf(u37,vv.y,g1); g2=fmaf(u38,vv.z,g2); g3=fmaf(u39,vv.w,g3);
        vv = h4[10]; g0=fmaf(u40,vv.x,g0); g1=fmaf(u41,vv.y,g1); g2=fmaf(u42,vv.z,g2); g3=fmaf(u43,vv.w,g3);
        vv = h4[11]; g0=fmaf(u44,vv.x,g0); g1=fmaf(u45,vv.y,g1); g2=fmaf(u46,vv.z,g2); g3=fmaf(u47,vv.w,g3);
        vv = h4[12]; g0=fmaf(u48,vv.x,g0); g1=fmaf(u49,vv.y,g1); g2=fmaf(u50,vv.z,g2); g3=fmaf(u51,vv.w,g3);
        vv = h4[13]; g0=fmaf(u52,vv.x,g0); g1=fmaf(u53,vv.y,g1); g2=fmaf(u54,vv.z,g2); g3=fmaf(u55,vv.w,g3);
        vv = h4[14]; g0=fmaf(u56,vv.x,g0); g1=fmaf(u57,vv.y,g1); g2=fmaf(u58,vv.z,g2); g3=fmaf(u59,vv.w,g3);
        vv = h4[15]; g0=fmaf(u60,vv.x,g0); g1=fmaf(u61,vv.y,g1); g2=fmaf(u62,vv.z,g2); g3=fmaf(u63,vv.w,g3);
        vv = h4[16]; g0=fmaf(u64,vv.x,g0); g1=fmaf(u65,vv.y,g1); g2=fmaf(u66,vv.z,g2); g3=fmaf(u67,vv.w,g3);
        vv = h4[17]; g0=fmaf(u68,vv.x,g0); g1=fmaf(u69,vv.y,g1); g2=fmaf(u70,vv.z,g2); g3=fmaf(u71,vv.w,g3);
        vv = h4[18]; g0=fmaf(u72,vv.x,g0); g1=fmaf(u73,vv.y,g1); g2=fmaf(u74,vv.z,g2); g3=fmaf(u75,vv.w,g3);
        vv = h4[19]; g0=fmaf(u76,vv.x,g0); g1=fmaf(u77,vv.y,g1); g2=fmaf(u78,vv.z,g2); g3=fmaf(u79,vv.w,g3);
        vv = h4[20]; g0=fmaf(u80,vv.x,g0); g1=fmaf(u81,vv.y,g1); g2=fmaf(u82,vv.z,g2); g3=fmaf(u83,vv.w,g3);
        vv = h4[21]; g0=fmaf(u84,vv.x,g0); g1=fmaf(u85,vv.y,g1); g2=fmaf(u86,vv.z,g2); g3=fmaf(u87,vv.w,g3);
        vv = h4[22]; g0=fmaf(u88,vv.x,g0); g1=fmaf(u89,vv.y,g1); g2=fmaf(u90,vv.z,g2); g3=fmaf(u91,vv.w,g3);
        vv = h4[23]; g0=fmaf(u92,vv.x,g0); g1=fmaf(u93,vv.y,g1); g2=fmaf(u94,vv.z,g2); g3=fmaf(u95,vv.w,g3);
        vv = h4[24]; g0=fmaf(u96,vv.x,g0); g1=fmaf(u97,vv.y,g1); g2=fmaf(u98,vv.z,g2); g3=fmaf(u99,vv.w,g3);
        const float ah = bh + ((g0 + g1) + (g2 + g3));

        if (tid < 2 * HDIM) {
            gates[tid] = ai + ah;                 // r, z rows
        } else if (tid < G3) {
            gates[tid]        = ai;               // i_n
            ghn[tid - 2*HDIM] = ah;               // h_n
        }
        if (tid < XDIM) x_lds[nxt][tid] = xpf;
        __syncthreads();

        // ---- phase B: nonlinearity + state update ----
        if (tid < HDIM) {
            const float r  = fast_sigmoid(gates[tid]);
            const float z  = fast_sigmoid(gates[HDIM + tid]);
            const float n  = fast_tanh(fmaf(r, ghn[tid], gates[2*HDIM + tid]));
            const float ho = h_lds[cur][tid];
            const float hv = fmaf(z, ho - n, n);  // (1-z)*n + z*h
            h_lds[nxt][tid] = hv;
            sum += hv;
            mx = fmaxf(mx, hv);
        }
        __syncthreads();
    }

    // ---- pooling + output linear ----
    if (tid < HDIM) {
        feat[tid]        = sum / len0[b];
        feat[HDIM + tid] = mx;
    }
    __syncthreads();

    if (tid < NCLS) {
        float acc = b_out[tid];
        #pragma unroll 4
        for (int k = 0; k < 2 * HDIM; ++k)
            acc = fmaf(W_out[tid * 2 * HDIM + k], feat[k], acc);
        out[b * NCLS + tid] = acc;
    }
}

extern "C" void kernel_launch(void* const* d_in, const int* in_sizes, int n_in,
                              void* d_out, int out_size, void* d_ws, size_t ws_size,
                              hipStream_t stream)
{
    const float* mfcc0 = (const float*)d_in[0];
    const float* mfcc1 = (const float*)d_in[1];
    const float* mfcc2 = (const float*)d_in[2];
    const float* len0  = (const float*)d_in[3];
    const float* W_ih  = (const float*)d_in[4];
    const float* W_hh  = (const float*)d_in[5];
    const float* b_ih  = (const float*)d_in[6];
    const float* b_hh  = (const float*)d_in[7];
    const float* W_out = (const float*)d_in[8];
    const float* b_out = (const float*)d_in[9];
    float* out = (float*)d_out;

    gru_persistent<<<BATCH, 320, 0, stream>>>(
        mfcc0, mfcc1, mfcc2, len0, W_ih, W_hh, b_ih, b_hh, W_out, b_out, out);
}

// Round 8
// 931.134 us; speedup vs baseline: 2.7755x; 1.7866x over previous
//
#include <hip/hip_runtime.h>
#include <math.h>

// T=1000, B=256, F_IN=13 x3 -> 39 features, H=100, 3H=300 (gate order r,z,n), 20 classes
#define T_STEPS 1000
#define BATCH   256
#define FIN     13
#define XDIM    39
#define HDIM    100
#define G3      300
#define NCLS    20
#define NTHR    960      // 3 thread-parts per gate row; parts are wave-aligned (5 waves each)
#define VLEN    160      // V = [x(39)+pad(1) | h(100) | zero-pad(20)]
#define CHUNK   52       // floats per part = 13 float4

__device__ __forceinline__ float fast_sigmoid(float v) {
    return 1.f / (1.f + __expf(-v));
}
__device__ __forceinline__ float fast_tanh(float v) {
    const float c = fminf(fmaxf(v, -15.f), 15.f);
    const float e = __expf(2.f * c);
    return (e - 1.f) / (e + 1.f);
}

// R4-R7 lessons: the allocator will NOT hold ~139 weight floats/thread (remat /
// alloca / pin-shuffle all lose). It holds ~50 happily (R4 kept 88 VGPRs).
// So: 3 threads per gate row, 52 weights each, uniform scalar init, and an
// explicit launch_bounds(960,4) contract (cap 128 VGPR >= ~90 need -> no
// pressure -> no remat). Part p of row g covers:
//   p0: V[0:52)   = x(39)+pad, h[0:12) with ZERO weights (keeps i_n pure)
//   p1: V[40:92)  = h[0:52)
//   p2: V[92:144) = h[52:100) + zero-pad
__launch_bounds__(NTHR, 4)
__global__ void gru_persistent(const float* __restrict__ mfcc0,
                               const float* __restrict__ mfcc1,
                               const float* __restrict__ mfcc2,
                               const float* __restrict__ len0,
                               const float* __restrict__ W_ih,
                               const float* __restrict__ W_hh,
                               const float* __restrict__ b_ih,
                               const float* __restrict__ b_hh,
                               const float* __restrict__ W_out,
                               const float* __restrict__ b_out,
                               float* __restrict__ out)
{
    const int b   = blockIdx.x;
    const int tid = threadIdx.x;
    const int p   = tid / 320;                    // part 0,1,2 (wave-aligned)
    const int g0  = tid % 320;                    // row id within part
    const int g   = (g0 < G3) ? g0 : (G3 - 1);    // clamped; stores guarded by g0

    __shared__ __align__(16) float V[2][VLEN];    // [x | h | pad] ping-pong
    __shared__ float part[3 * G3];                // partial dot per (p, row)
    __shared__ float feat[2 * HDIM];

    // ---- one-time setup (uniform control flow; scalars only — no aggregates) ----
    const float* src = (p == 0) ? (W_ih + g * XDIM)
                                : (W_hh + g * HDIM + ((p == 2) ? CHUNK : 0));
    const int   c    = (p == 0) ? XDIM : ((p == 1) ? CHUNK : (HDIM - CHUNK));
    const float bias = (p == 0) ? b_ih[g] : ((p == 1) ? b_hh[g] : 0.f);
    const int   vb0  = (p == 0) ? 0 : ((p == 1) ? 10 : 23);   // float4-unit base

    float w00 = ( 0 < c) ? src[ 0] : 0.f, w01 = ( 1 < c) ? src[ 1] : 0.f;
    float w02 = ( 2 < c) ? src[ 2] : 0.f, w03 = ( 3 < c) ? src[ 3] : 0.f;
    float w04 = ( 4 < c) ? src[ 4] : 0.f, w05 = ( 5 < c) ? src[ 5] : 0.f;
    float w06 = ( 6 < c) ? src[ 6] : 0.f, w07 = ( 7 < c) ? src[ 7] : 0.f;
    float w08 = ( 8 < c) ? src[ 8] : 0.f, w09 = ( 9 < c) ? src[ 9] : 0.f;
    float w10 = (10 < c) ? src[10] : 0.f, w11 = (11 < c) ? src[11] : 0.f;
    float w12 = (12 < c) ? src[12] : 0.f, w13 = (13 < c) ? src[13] : 0.f;
    float w14 = (14 < c) ? src[14] : 0.f, w15 = (15 < c) ? src[15] : 0.f;
    float w16 = (16 < c) ? src[16] : 0.f, w17 = (17 < c) ? src[17] : 0.f;
    float w18 = (18 < c) ? src[18] : 0.f, w19 = (19 < c) ? src[19] : 0.f;
    float w20 = (20 < c) ? src[20] : 0.f, w21 = (21 < c) ? src[21] : 0.f;
    float w22 = (22 < c) ? src[22] : 0.f, w23 = (23 < c) ? src[23] : 0.f;
    float w24 = (24 < c) ? src[24] : 0.f, w25 = (25 < c) ? src[25] : 0.f;
    float w26 = (26 < c) ? src[26] : 0.f, w27 = (27 < c) ? src[27] : 0.f;
    float w28 = (28 < c) ? src[28] : 0.f, w29 = (29 < c) ? src[29] : 0.f;
    float w30 = (30 < c) ? src[30] : 0.f, w31 = (31 < c) ? src[31] : 0.f;
    float w32 = (32 < c) ? src[32] : 0.f, w33 = (33 < c) ? src[33] : 0.f;
    float w34 = (34 < c) ? src[34] : 0.f, w35 = (35 < c) ? src[35] : 0.f;
    float w36 = (36 < c) ? src[36] : 0.f, w37 = (37 < c) ? src[37] : 0.f;
    float w38 = (38 < c) ? src[38] : 0.f, w39 = (39 < c) ? src[39] : 0.f;
    float w40 = (40 < c) ? src[40] : 0.f, w41 = (41 < c) ? src[41] : 0.f;
    float w42 = (42 < c) ? src[42] : 0.f, w43 = (43 < c) ? src[43] : 0.f;
    float w44 = (44 < c) ? src[44] : 0.f, w45 = (45 < c) ? src[45] : 0.f;
    float w46 = (46 < c) ? src[46] : 0.f, w47 = (47 < c) ? src[47] : 0.f;
    float w48 = (48 < c) ? src[48] : 0.f, w49 = (49 < c) ? src[49] : 0.f;
    float w50 = (50 < c) ? src[50] : 0.f, w51 = (51 < c) ? src[51] : 0.f;

    // ---- per-thread x streaming source (threads 0..38, all in part 0) ----
    const float* xsrc = mfcc0;
    int xoff = 0;
    if (tid < XDIM) {
        const int f = tid % FIN;
        xsrc = (tid < FIN) ? mfcc0 : (tid < 2 * FIN ? mfcc1 : mfcc2);
        xoff = b * FIN + f;
    }

    // ---- init: zero both V buffers (h=0, pads=0), then x(t=0) ----
    if (tid < VLEN) { V[0][tid] = 0.f; V[1][tid] = 0.f; }
    if (tid < XDIM) V[0][tid] = xsrc[xoff];
    __syncthreads();

    float sum = 0.f;
    float mx  = -INFINITY;

    for (int t = 0; t < T_STEPS; ++t) {
        const int cur = t & 1;
        const int nxt = cur ^ 1;

        float xpf = 0.f;   // prefetch x(t+1) during compute
        if (tid < XDIM && (t + 1) < T_STEPS)
            xpf = xsrc[(size_t)(t + 1) * (BATCH * FIN) + xoff];

        // ---- phase A: 13 broadcast float4 reads x 4 FMAs (uniform body) ----
        const float4* V4 = (const float4*)V[cur];
        float a0 = 0.f, a1 = 0.f, a2 = 0.f, a3 = 0.f;
        float4 vv;
        vv = V4[vb0+ 0]; a0=fmaf(w00,vv.x,a0); a1=fmaf(w01,vv.y,a1); a2=fmaf(w02,vv.z,a2); a3=fmaf(w03,vv.w,a3);
        vv = V4[vb0+ 1]; a0=fmaf(w04,vv.x,a0); a1=fmaf(w05,vv.y,a1); a2=fmaf(w06,vv.z,a2); a3=fmaf(w07,vv.w,a3);
        vv = V4[vb0+ 2]; a0=fmaf(w08,vv.x,a0); a1=fmaf(w09,vv.y,a1); a2=fmaf(w10,vv.z,a2); a3=fmaf(w11,vv.w,a3);
        vv = V4[vb0+ 3]; a0=fmaf(w12,vv.x,a0); a1=fmaf(w13,vv.y,a1); a2=fmaf(w14,vv.z,a2); a3=fmaf(w15,vv.w,a3);
        vv = V4[vb0+ 4]; a0=fmaf(w16,vv.x,a0); a1=fmaf(w17,vv.y,a1); a2=fmaf(w18,vv.z,a2); a3=fmaf(w19,vv.w,a3);
        vv = V4[vb0+ 5]; a0=fmaf(w20,vv.x,a0); a1=fmaf(w21,vv.y,a1); a2=fmaf(w22,vv.z,a2); a3=fmaf(w23,vv.w,a3);
        vv = V4[vb0+ 6]; a0=fmaf(w24,vv.x,a0); a1=fmaf(w25,vv.y,a1); a2=fmaf(w26,vv.z,a2); a3=fmaf(w27,vv.w,a3);
        vv = V4[vb0+ 7]; a0=fmaf(w28,vv.x,a0); a1=fmaf(w29,vv.y,a1); a2=fmaf(w30,vv.z,a2); a3=fmaf(w31,vv.w,a3);
        vv = V4[vb0+ 8]; a0=fmaf(w32,vv.x,a0); a1=fmaf(w33,vv.y,a1); a2=fmaf(w34,vv.z,a2); a3=fmaf(w35,vv.w,a3);
        vv = V4[vb0+ 9]; a0=fmaf(w36,vv.x,a0); a1=fmaf(w37,vv.y,a1); a2=fmaf(w38,vv.z,a2); a3=fmaf(w39,vv.w,a3);
        vv = V4[vb0+10]; a0=fmaf(w40,vv.x,a0); a1=fmaf(w41,vv.y,a1); a2=fmaf(w42,vv.z,a2); a3=fmaf(w43,vv.w,a3);
        vv = V4[vb0+11]; a0=fmaf(w44,vv.x,a0); a1=fmaf(w45,vv.y,a1); a2=fmaf(w46,vv.z,a2); a3=fmaf(w47,vv.w,a3);
        vv = V4[vb0+12]; a0=fmaf(w48,vv.x,a0); a1=fmaf(w49,vv.y,a1); a2=fmaf(w50,vv.z,a2); a3=fmaf(w51,vv.w,a3);

        if (g0 < G3)
            part[p * G3 + g0] = bias + ((a0 + a1) + (a2 + a3));
        if (tid < XDIM) V[nxt][tid] = xpf;         // stage x(t+1)
        __syncthreads();

        // ---- phase B: nonlinearity + state update (threads 0..99) ----
        if (tid < HDIM) {
            const float r  = fast_sigmoid(part[tid] + part[G3 + tid] + part[2*G3 + tid]);
            const float z  = fast_sigmoid(part[HDIM + tid] + part[G3 + HDIM + tid] + part[2*G3 + HDIM + tid]);
            const float hn = part[G3 + 2*HDIM + tid] + part[2*G3 + 2*HDIM + tid];  // includes b_hh
            const float n  = fast_tanh(fmaf(r, hn, part[2*HDIM + tid]));           // i_n includes b_ih
            const float ho = V[cur][XDIM + 1 + tid];
            const float hv = fmaf(z, ho - n, n);   // (1-z)*n + z*h
            V[nxt][XDIM + 1 + tid] = hv;
            sum += hv;
            mx = fmaxf(mx, hv);
        }
        __syncthreads();
    }

    // ---- pooling + output linear ----
    if (tid < HDIM) {
        feat[tid]        = sum / len0[b];
        feat[HDIM + tid] = mx;
    }
    __syncthreads();

    if (tid < NCLS) {
        float acc = b_out[tid];
        #pragma unroll 4
        for (int k = 0; k < 2 * HDIM; ++k)
            acc = fmaf(W_out[tid * 2 * HDIM + k], feat[k], acc);
        out[b * NCLS + tid] = acc;
    }
}

extern "C" void kernel_launch(void* const* d_in, const int* in_sizes, int n_in,
                              void* d_out, int out_size, void* d_ws, size_t ws_size,
                              hipStream_t stream)
{
    const float* mfcc0 = (const float*)d_in[0];
    const float* mfcc1 = (const float*)d_in[1];
    const float* mfcc2 = (const float*)d_in[2];
    const float* len0  = (const float*)d_in[3];
    const float* W_ih  = (const float*)d_in[4];
    const float* W_hh  = (const float*)d_in[5];
    const float* b_ih  = (const float*)d_in[6];
    const float* b_hh  = (const float*)d_in[7];
    const float* W_out = (const float*)d_in[8];
    const float* b_out = (const float*)d_in[9];
    float* out = (float*)d_out;

    gru_persistent<<<BATCH, NTHR, 0, stream>>>(
        mfcc0, mfcc1, mfcc2, len0, W_ih, W_hh, b_ih, b_hh, W_out, b_out, out);
}